// Round 4
// baseline (85.341 us; speedup 1.0000x reference)
//
#include <hip/hip_runtime.h>

// B=64, L=256, C_IN=5, KERNEL=4, C=8. S = 253 real scan steps, padded to 256
// with zero increments (identity steps). Output per batch: 8+64+512+4096 = 4680.
//
// Grid: 512 blocks x 64 threads. block = (batch b, tensor index i).
// 512 blocks / 256 CUs = 2 single-wave blocks per CU -> only 2 waves share
// each CU's LDS pipe (round-3 config had 4: measured LDS-throughput-bound at
// 162 cyc/iter). The scan is specialized on block-uniform i via switch so
// a = dx[i] comes free from the row registers (kills one ds_read_b32).
#define L_IN    256
#define S_STEPS 253
#define CIN     5

// Per-iter LDS ops (per wave): 2x ds_read_b32 (own=dx[k], bb=dx[j], gathers
// within one 32B row -> <=2-way bank aliasing, free) + 2x ds_read_b128
// (row broadcast). Depth-4 register pipeline hides LDS latency.
template<int I>
__device__ __forceinline__ void scan_and_store(
    const float (* __restrict__ dxs)[8], int j, int k, int b, int lane,
    float* __restrict__ out)
{
    float s1 = 0.f, s2 = 0.f, s3 = 0.f;
    float s4[8];
    #pragma unroll
    for (int l = 0; l < 8; ++l) s4[l] = 0.f;

    const float4* __restrict__ dx4 = reinterpret_cast<const float4*>(&dxs[0][0]);

    float own_p[4], bb_p[4];
    float4 r0_p[4], r1_p[4];
    #pragma unroll
    for (int u = 0; u < 4; ++u) {
        own_p[u] = dxs[u][k];
        bb_p[u]  = dxs[u][j];
        r0_p[u]  = dx4[2 * u];
        r1_p[u]  = dx4[2 * u + 1];
    }

    for (int tb = 0; tb < 256; tb += 4) {
        #pragma unroll
        for (int u = 0; u < 4; ++u) {
            const int tn = tb + u + 4;   // prefetch row (<= 259, zeroed pad)
            float  own_n = dxs[tn][k];
            float  bb_n  = dxs[tn][j];
            float4 r0_n  = dx4[2 * tn];
            float4 r1_n  = dx4[2 * tn + 1];

            const float own = own_p[u];   // dx[k] == cc
            const float bb  = bb_p[u];    // dx[j]
            const float4 r0 = r0_p[u];    // dx[0..3]
            const float4 r1 = r1_p[u];    // dx[4..7]
            // a = dx[I]: compile-time row component (block-uniform i)
            const float a =
                (I == 0) ? r0.x : (I == 1) ? r0.y : (I == 2) ? r0.z :
                (I == 3) ? r0.w : (I == 4) ? r1.x : (I == 5) ? r1.y :
                (I == 6) ? r1.z : r1.w;

            // rank-1 factored update (uses OLD s1,s2,s3)
            const float t2    = fmaf(a, 0.5f, s1);
            const float t3    = fmaf(s1, 0.5f, a * (1.0f / 6.0f));
            const float t4    = fmaf(s1, (1.0f / 6.0f), a * (1.0f / 24.0f));
            const float coef3 = fmaf(bb, t3, s2);
            const float uu    = fmaf(bb, t4, 0.5f * s2);
            const float coef4 = fmaf(own, uu, s3);   // own == cc
            s4[0] = fmaf(coef4, r0.x, s4[0]);
            s4[1] = fmaf(coef4, r0.y, s4[1]);
            s4[2] = fmaf(coef4, r0.z, s4[2]);
            s4[3] = fmaf(coef4, r0.w, s4[3]);
            s4[4] = fmaf(coef4, r1.x, s4[4]);
            s4[5] = fmaf(coef4, r1.y, s4[5]);
            s4[6] = fmaf(coef4, r1.z, s4[6]);
            s4[7] = fmaf(coef4, r1.w, s4[7]);
            s3 = fmaf(coef3, own, s3);
            s2 = fmaf(t2, bb, s2);
            s1 += a;

            own_p[u] = own_n; bb_p[u] = bb_n;
            r0_p[u] = r0_n;   r1_p[u] = r1_n;
        }
    }

    // epilogue: out[b] = [s1(8) | s2(64) | s3(512) | s4(4096)]
    float* __restrict__ ob = out + (size_t)b * 4680;
    if (lane == 0) ob[I] = s1;
    if (k == 0)    ob[8 + I * 8 + j] = s2;
    ob[72 + (I * 8 + j) * 8 + k] = s3;
    float4* o4 = reinterpret_cast<float4*>(ob + 584 + (size_t)((I * 8 + j) * 8 + k) * 8);
    o4[0] = make_float4(s4[0], s4[1], s4[2], s4[3]);
    o4[1] = make_float4(s4[4], s4[5], s4[6], s4[7]);
}

__global__ __launch_bounds__(64) void fused_sig_kernel(
    const float* __restrict__ inp,
    const float* __restrict__ w1, const float* __restrict__ b1,
    const float* __restrict__ w2, const float* __restrict__ b2,
    const float* __restrict__ w3, const float* __restrict__ b3,
    float* __restrict__ out)
{
    const int blk = blockIdx.x;     // 0..511
    const int b   = blk >> 3;       // batch
    const int i   = blk & 7;        // tensor index i (block-uniform)
    const int tid = threadIdx.x;    // 0..63

    __shared__ float path[S_STEPS][8];
    // rows 0..252: increments; 253..255: zeros (identity); 256..263: slop
    __shared__ __align__(16) float dxs[264][8];

    // ---------------- phase 1: conv augment -> path (4 positions/thread) ---
    const float* __restrict__ x = inp + b * (L_IN * CIN);
    #pragma unroll
    for (int p = 0; p < 4; ++p) {
        const int t = tid + p * 64;
        if (t < S_STEPS) {
            float h1[8];
            #pragma unroll
            for (int o = 0; o < 8; ++o) h1[o] = b1[o];
            #pragma unroll
            for (int kk = 0; kk < 4; ++kk) {
                #pragma unroll
                for (int ci = 0; ci < CIN; ++ci) {
                    float v = x[(t + kk) * CIN + ci];
                    #pragma unroll
                    for (int o = 0; o < 8; ++o) h1[o] = fmaf(v, w1[o * 20 + ci * 4 + kk], h1[o]);
                }
            }
            float r1v[8];
            #pragma unroll
            for (int o = 0; o < 8; ++o) r1v[o] = h1[o] > 0.f ? h1[o] : 0.f;
            float h2[8];
            #pragma unroll
            for (int o = 0; o < 8; ++o) h2[o] = b2[o];
            #pragma unroll
            for (int q = 0; q < 8; ++q) {
                #pragma unroll
                for (int o = 0; o < 8; ++o) h2[o] = fmaf(r1v[q], w2[o * 8 + q], h2[o]);
            }
            float r2v[8];
            #pragma unroll
            for (int o = 0; o < 8; ++o) r2v[o] = h2[o] > 0.f ? h2[o] : 0.f;
            float h30 = b3[0], h31 = b3[1];
            #pragma unroll
            for (int q = 0; q < 8; ++q) {
                h30 = fmaf(r2v[q], w3[q], h30);
                h31 = fmaf(r2v[q], w3[8 + q], h31);
            }
            #pragma unroll
            for (int c = 0; c < 5; ++c) path[t][c] = x[(t + 3) * CIN + c];
            path[t][5] = (float)(t + 3) * (1.0f / 255.0f);
            path[t][6] = h30;
            path[t][7] = h31;
        }
    }
    // zero pad rows 253..260 (8 rows x 8 = 64 entries, one per thread)
    dxs[253 + (tid >> 3)][tid & 7] = 0.f;
    __syncthreads();
    #pragma unroll
    for (int p = 0; p < 4; ++p) {
        const int t = tid + p * 64;
        if (t < S_STEPS) {
            #pragma unroll
            for (int c = 0; c < 8; ++c) {
                float prev = (t > 0) ? path[t - 1][c] : 0.f;
                dxs[t][c] = path[t][c] - prev;
            }
        }
    }
    __syncthreads();

    // ---------------- phase 2: scan, specialized on i ----------------
    const int lane = tid;
    const int j    = lane >> 3;
    const int k    = lane & 7;
    switch (i) {
        case 0: scan_and_store<0>(dxs, j, k, b, lane, out); break;
        case 1: scan_and_store<1>(dxs, j, k, b, lane, out); break;
        case 2: scan_and_store<2>(dxs, j, k, b, lane, out); break;
        case 3: scan_and_store<3>(dxs, j, k, b, lane, out); break;
        case 4: scan_and_store<4>(dxs, j, k, b, lane, out); break;
        case 5: scan_and_store<5>(dxs, j, k, b, lane, out); break;
        case 6: scan_and_store<6>(dxs, j, k, b, lane, out); break;
        default: scan_and_store<7>(dxs, j, k, b, lane, out); break;
    }
}

extern "C" void kernel_launch(void* const* d_in, const int* in_sizes, int n_in,
                              void* d_out, int out_size, void* d_ws, size_t ws_size,
                              hipStream_t stream)
{
    const float* inp = (const float*)d_in[0];
    const float* w1  = (const float*)d_in[1];
    const float* b1  = (const float*)d_in[2];
    const float* w2  = (const float*)d_in[3];
    const float* b2  = (const float*)d_in[4];
    const float* w3  = (const float*)d_in[5];
    const float* b3  = (const float*)d_in[6];
    float* out = (float*)d_out;

    fused_sig_kernel<<<512, 64, 0, stream>>>(inp, w1, b1, w2, b2, w3, b3, out);
}